// Round 3
// baseline (299.512 us; speedup 1.0000x reference)
//
#include <hip/hip_runtime.h>
#include <hip/hip_bf16.h>
#include <math.h>

#define NTIME 20
#define V 128
#define F 128
constexpr float ALPHA = 0.2f;
constexpr float NEGV = -9000000000000000.0f;

// ---------------- kernel 0: Wa[s] = W @ a_s  (128x128 each, f32) ----------------
// grid (128, 2), block 128.  Wa[(s*F + i)*F + k] = sum_m W[i][m] * a[s*F+m][k]
__global__ __launch_bounds__(128) void k_wa(const float* __restrict__ W,
                                            const float* __restrict__ a,
                                            float* __restrict__ Wa) {
  const int i = blockIdx.x;
  const int s = blockIdx.y;
  const int k = threadIdx.x;
  __shared__ float wrow[F];
  wrow[k] = W[i * F + k];
  __syncthreads();
  const float* as = a + s * F * F;
  float acc = 0.f;
#pragma unroll 8
  for (int m = 0; m < F; ++m) acc += wrow[m] * as[m * F + k];
  Wa[(s * F + i) * F + k] = acc;
}

// ---------------- kernel 1: [Wh|E1|E2] = h @ [W|Wa1|Wa2] ----------------
// M=2560, K=128, N=384 logically. grid (40, 6): blockIdx.x = row tile (64 rows),
// blockIdx.y: y>>1 selects matrix {Wh,E1,E2}, y&1 selects 64-col half.
__global__ __launch_bounds__(256) void k_gemm(const float* __restrict__ h,
                                              const float* __restrict__ W,
                                              const float* __restrict__ Wa,
                                              float* __restrict__ Wh,
                                              float* __restrict__ E1,
                                              float* __restrict__ E2) {
  __shared__ float Alds[64][129];   // padded: conflict-free scalar reads
  __shared__ float Blds[128][64];   // float4 reads, 2-way bank alias (free)
  const int tid = threadIdx.x;
  const int rb = blockIdx.x * 64;
  const int matc = blockIdx.y >> 1;
  const int cb = (blockIdx.y & 1) * 64;

  // stage A tile: 64 rows x 128 k of h (f32), float4 loads
#pragma unroll
  for (int p = 0; p < 8; ++p) {
    int id = tid + p * 256;            // 0..2047 chunks of 4 f32 (32 chunks/row)
    int row = id >> 5;
    int c0 = (id & 31) * 4;
    float4 v = *reinterpret_cast<const float4*>(&h[(rb + row) * F + c0]);
    Alds[row][c0 + 0] = v.x; Alds[row][c0 + 1] = v.y;
    Alds[row][c0 + 2] = v.z; Alds[row][c0 + 3] = v.w;
  }
  // stage B tile: 128 k x 64 cols (from W or Wa, both f32 row-major 128x128)
  const float* src = (matc == 0) ? W : (Wa + (matc - 1) * F * F);
#pragma unroll
  for (int p = 0; p < 8; ++p) {
    int id = tid + p * 256;            // 0..2047 chunks of 4 f32 (16 chunks/row)
    int k = id >> 4;
    int c0 = (id & 15) * 4;
    float4 v = *reinterpret_cast<const float4*>(&src[k * F + cb + c0]);
    Blds[k][c0 + 0] = v.x; Blds[k][c0 + 1] = v.y;
    Blds[k][c0 + 2] = v.z; Blds[k][c0 + 3] = v.w;
  }
  __syncthreads();

  const int tx = tid & 15;
  const int ty = tid >> 4;
  float acc[4][4] = {};
#pragma unroll 4
  for (int k = 0; k < 128; ++k) {
    float4 bv = *reinterpret_cast<const float4*>(&Blds[k][tx * 4]);
    float a0 = Alds[ty * 4 + 0][k];
    float a1 = Alds[ty * 4 + 1][k];
    float a2 = Alds[ty * 4 + 2][k];
    float a3 = Alds[ty * 4 + 3][k];
    acc[0][0] += a0 * bv.x; acc[0][1] += a0 * bv.y; acc[0][2] += a0 * bv.z; acc[0][3] += a0 * bv.w;
    acc[1][0] += a1 * bv.x; acc[1][1] += a1 * bv.y; acc[1][2] += a1 * bv.z; acc[1][3] += a1 * bv.w;
    acc[2][0] += a2 * bv.x; acc[2][1] += a2 * bv.y; acc[2][2] += a2 * bv.z; acc[2][3] += a2 * bv.w;
    acc[3][0] += a3 * bv.x; acc[3][1] += a3 * bv.y; acc[3][2] += a3 * bv.z; acc[3][3] += a3 * bv.w;
  }

  float* Dp = (matc == 0) ? Wh : ((matc == 1) ? E1 : E2);
  const int gr0 = rb + ty * 4;
  const int c0 = cb + tx * 4;
#pragma unroll
  for (int i = 0; i < 4; ++i) {
    float4 v;
    v.x = acc[i][0]; v.y = acc[i][1]; v.z = acc[i][2]; v.w = acc[i][3];
    *reinterpret_cast<float4*>(&Dp[(gr0 + i) * F + c0]) = v;
  }
}

// ---------------- kernel 2: attention + softmax + aggregate + elu ----------------
// grid 2560 (= t*128 + b), block 128 (thread = f column). LDS e[V][F] = 64 KB.
// Each thread owns one f-column: no cross-thread data flow, no syncs needed.
__global__ __launch_bounds__(128) void k_attn(const float* __restrict__ Wh,
                                              const float* __restrict__ E1,
                                              const float* __restrict__ E2,
                                              const float* __restrict__ adj,
                                              float* __restrict__ out,
                                              float* __restrict__ att) {
  __shared__ float e[V][F];
  const int t = blockIdx.x >> 7;
  const int b = blockIdx.x & 127;
  const int f = threadIdx.x;
  const int r = t * V + b;

  const float e1 = E1[r * F + f];
  const float* E2t = E2 + t * V * F;

  // pass 1: fill e + running max (adj branch is wave-uniform)
  float m = -INFINITY;
#pragma unroll 4
  for (int j = 0; j < V; ++j) {
    float av = adj[b * V + j];
    float ev;
    if (av > 0.f) {
      float x = e1 + E2t[j * F + f];
      ev = (x > 0.f) ? x : ALPHA * x;
    } else {
      ev = NEGV;
    }
    e[j][f] = ev;
    m = fmaxf(m, ev);
  }
  // pass 2: exp + sum (thread-private column)
  float s = 0.f;
#pragma unroll 4
  for (int j = 0; j < V; ++j) {
    float p = __expf(e[j][f] - m);
    e[j][f] = p;
    s += p;
  }
  const float inv = 1.f / s;

  // pass 3: normalize+write attention, accumulate h_prime
  const float* Wht = Wh + t * V * F;
  float* attb = att + (size_t)r * (V * F);
  float hp = 0.f;
#pragma unroll 4
  for (int j = 0; j < V; ++j) {
    float p = e[j][f];
    hp += p * Wht[j * F + f];
    attb[j * F + f] = p * inv;
  }
  hp *= inv;
  out[r * F + f] = hp > 0.f ? hp : __expf(hp) - 1.f;
}

extern "C" void kernel_launch(void* const* d_in, const int* in_sizes, int n_in,
                              void* d_out, int out_size, void* d_ws, size_t ws_size,
                              hipStream_t stream) {
  (void)in_sizes; (void)n_in; (void)out_size; (void)ws_size;
  const float* h   = (const float*)d_in[0];
  const float* adj = (const float*)d_in[1];
  const float* W   = (const float*)d_in[2];
  const float* a   = (const float*)d_in[3];

  // workspace layout (f32): Wh[2560*128] | E1[2560*128] | E2[2560*128] | Wa[2*128*128]
  float* Wh = (float*)d_ws;
  float* E1 = Wh + NTIME * V * F;
  float* E2 = E1 + NTIME * V * F;
  float* Wa = E2 + NTIME * V * F;

  float* out = (float*)d_out;                    // (T, V, F)
  float* att = out + NTIME * V * F;              // (T, V, V, F)

  k_wa<<<dim3(128, 2), 128, 0, stream>>>(W, a, Wa);
  k_gemm<<<dim3(40, 6), 256, 0, stream>>>(h, W, Wa, Wh, E1, E2);
  k_attn<<<dim3(NTIME * V), 128, 0, stream>>>(Wh, E1, E2, adj, out, att);
}

// Round 4
// 246.089 us; speedup vs baseline: 1.2171x; 1.2171x over previous
//
#include <hip/hip_runtime.h>
#include <hip/hip_bf16.h>
#include <math.h>

#define NTIME 20
#define V 128
#define F 128
constexpr float ALPHA = 0.2f;

// ---------------- kernel 0: Wa[s] = W @ a_s  (128x128 each, f32) ----------------
__global__ __launch_bounds__(128) void k_wa(const float* __restrict__ W,
                                            const float* __restrict__ a,
                                            float* __restrict__ Wa) {
  const int i = blockIdx.x;
  const int s = blockIdx.y;
  const int k = threadIdx.x;
  __shared__ float wrow[F];
  wrow[k] = W[i * F + k];
  __syncthreads();
  const float* as = a + s * F * F;
  float acc = 0.f;
#pragma unroll 8
  for (int m = 0; m < F; ++m) acc += wrow[m] * as[m * F + k];
  Wa[(s * F + i) * F + k] = acc;
}

// ---------------- kernel 1: [Wh|E1|E2] = h @ [W|Wa1|Wa2] ----------------
__global__ __launch_bounds__(256) void k_gemm(const float* __restrict__ h,
                                              const float* __restrict__ W,
                                              const float* __restrict__ Wa,
                                              float* __restrict__ Wh,
                                              float* __restrict__ E1,
                                              float* __restrict__ E2) {
  __shared__ float Alds[64][129];
  __shared__ float Blds[128][64];
  const int tid = threadIdx.x;
  const int rb = blockIdx.x * 64;
  const int matc = blockIdx.y >> 1;
  const int cb = (blockIdx.y & 1) * 64;

#pragma unroll
  for (int p = 0; p < 8; ++p) {
    int id = tid + p * 256;
    int row = id >> 5;
    int c0 = (id & 31) * 4;
    float4 v = *reinterpret_cast<const float4*>(&h[(rb + row) * F + c0]);
    Alds[row][c0 + 0] = v.x; Alds[row][c0 + 1] = v.y;
    Alds[row][c0 + 2] = v.z; Alds[row][c0 + 3] = v.w;
  }
  const float* src = (matc == 0) ? W : (Wa + (matc - 1) * F * F);
#pragma unroll
  for (int p = 0; p < 8; ++p) {
    int id = tid + p * 256;
    int k = id >> 4;
    int c0 = (id & 15) * 4;
    float4 v = *reinterpret_cast<const float4*>(&src[k * F + cb + c0]);
    Blds[k][c0 + 0] = v.x; Blds[k][c0 + 1] = v.y;
    Blds[k][c0 + 2] = v.z; Blds[k][c0 + 3] = v.w;
  }
  __syncthreads();

  const int tx = tid & 15;
  const int ty = tid >> 4;
  float acc[4][4] = {};
#pragma unroll 4
  for (int k = 0; k < 128; ++k) {
    float4 bv = *reinterpret_cast<const float4*>(&Blds[k][tx * 4]);
    float a0 = Alds[ty * 4 + 0][k];
    float a1 = Alds[ty * 4 + 1][k];
    float a2 = Alds[ty * 4 + 2][k];
    float a3 = Alds[ty * 4 + 3][k];
    acc[0][0] += a0 * bv.x; acc[0][1] += a0 * bv.y; acc[0][2] += a0 * bv.z; acc[0][3] += a0 * bv.w;
    acc[1][0] += a1 * bv.x; acc[1][1] += a1 * bv.y; acc[1][2] += a1 * bv.z; acc[1][3] += a1 * bv.w;
    acc[2][0] += a2 * bv.x; acc[2][1] += a2 * bv.y; acc[2][2] += a2 * bv.z; acc[2][3] += a2 * bv.w;
    acc[3][0] += a3 * bv.x; acc[3][1] += a3 * bv.y; acc[3][2] += a3 * bv.z; acc[3][3] += a3 * bv.w;
  }

  float* Dp = (matc == 0) ? Wh : ((matc == 1) ? E1 : E2);
  const int gr0 = rb + ty * 4;
  const int c0 = cb + tx * 4;
#pragma unroll
  for (int i = 0; i < 4; ++i) {
    float4 v;
    v.x = acc[i][0]; v.y = acc[i][1]; v.z = acc[i][2]; v.w = acc[i][3];
    *reinterpret_cast<float4*>(&Dp[(gr0 + i) * F + c0]) = v;
  }
}

// ---------------- kernel 2: attention, LDS-free recompute version ----------------
// One wave per (t,b) row; lane owns f-pair (2*lane, 2*lane+1). Block = 4 waves =
// 4 rows. No LDS -> occupancy bounded only by grid (10 waves/CU resident).
// Softmax without max-subtraction: unmasked logits are O(1) (exp safe in f32),
// masked -> exact 0. All-masked rows get an explicit uniform fallback.
__global__ __launch_bounds__(256) void k_attn(const float* __restrict__ Wh,
                                              const float* __restrict__ E1,
                                              const float* __restrict__ E2,
                                              const float* __restrict__ adj,
                                              float* __restrict__ out,
                                              float* __restrict__ att) {
  const int wid = threadIdx.x >> 6;
  const int lane = threadIdx.x & 63;
  const int r = blockIdx.x * 4 + wid;       // 0..2559
  const int t = r >> 7;
  const int b = r & 127;
  const int fc = lane * 2;

  const float2 e1v = *reinterpret_cast<const float2*>(E1 + r * F + fc);
  const float* E2t = E2 + t * V * F;
  const float* Wht = Wh + t * V * F;
  const float* adjb = adj + b * V;

  // pass A: denominator + weighted sum (skip masked j; branch is wave-uniform)
  float s0 = 0.f, s1 = 0.f, h0 = 0.f, h1 = 0.f;
#pragma unroll 4
  for (int j = 0; j < V; ++j) {
    if (adjb[j] > 0.f) {
      float2 e2 = *reinterpret_cast<const float2*>(E2t + j * F + fc);
      float x0 = e1v.x + e2.x, x1 = e1v.y + e2.y;
      x0 = x0 > 0.f ? x0 : ALPHA * x0;
      x1 = x1 > 0.f ? x1 : ALPHA * x1;
      float p0 = __expf(x0), p1 = __expf(x1);
      float2 w = *reinterpret_cast<const float2*>(Wht + j * F + fc);
      s0 += p0; s1 += p1;
      h0 += p0 * w.x; h1 += p1 * w.y;
    }
  }
  // all-masked fallback: reference softmax gives uniform 1/V (never taken for
  // this data, kept for exact semantics)
  const bool uni = (s0 == 0.f);
  if (uni) {
    s0 = s1 = (float)V;
    for (int j = 0; j < V; ++j) {
      float2 w = *reinterpret_cast<const float2*>(Wht + j * F + fc);
      h0 += w.x; h1 += w.y;
    }
  }
  const float inv0 = 1.f / s0, inv1 = 1.f / s1;

  // pass B: recompute p (E2 rows are L1/L2-hot), stream normalized att
  float* attb = att + (size_t)r * (V * F);
#pragma unroll 4
  for (int j = 0; j < V; ++j) {
    float2 o;
    if (uni) {
      o.x = inv0; o.y = inv1;
    } else if (adjb[j] > 0.f) {
      float2 e2 = *reinterpret_cast<const float2*>(E2t + j * F + fc);
      float x0 = e1v.x + e2.x, x1 = e1v.y + e2.y;
      x0 = x0 > 0.f ? x0 : ALPHA * x0;
      x1 = x1 > 0.f ? x1 : ALPHA * x1;
      o.x = __expf(x0) * inv0;
      o.y = __expf(x1) * inv1;
    } else {
      o.x = 0.f; o.y = 0.f;
    }
    *reinterpret_cast<float2*>(attb + j * F + fc) = o;
  }

  const float hp0 = h0 * inv0, hp1 = h1 * inv1;
  float2 ov;
  ov.x = hp0 > 0.f ? hp0 : __expf(hp0) - 1.f;
  ov.y = hp1 > 0.f ? hp1 : __expf(hp1) - 1.f;
  *reinterpret_cast<float2*>(out + r * F + fc) = ov;
}

extern "C" void kernel_launch(void* const* d_in, const int* in_sizes, int n_in,
                              void* d_out, int out_size, void* d_ws, size_t ws_size,
                              hipStream_t stream) {
  (void)in_sizes; (void)n_in; (void)out_size; (void)ws_size;
  const float* h   = (const float*)d_in[0];
  const float* adj = (const float*)d_in[1];
  const float* W   = (const float*)d_in[2];
  const float* a   = (const float*)d_in[3];

  float* Wh = (float*)d_ws;
  float* E1 = Wh + NTIME * V * F;
  float* E2 = E1 + NTIME * V * F;
  float* Wa = E2 + NTIME * V * F;

  float* out = (float*)d_out;                    // (T, V, F)
  float* att = out + NTIME * V * F;              // (T, V, V, F)

  k_wa<<<dim3(128, 2), 128, 0, stream>>>(W, a, Wa);
  k_gemm<<<dim3(40, 6), 256, 0, stream>>>(h, W, Wa, Wh, E1, E2);
  k_attn<<<dim3(640), 256, 0, stream>>>(Wh, E1, E2, adj, out, att);
}

// Round 5
// 210.289 us; speedup vs baseline: 1.4243x; 1.1702x over previous
//
#include <hip/hip_runtime.h>
#include <hip/hip_bf16.h>
#include <math.h>

#define NTIME 20
#define V 128
#define F 128
constexpr float ALPHA = 0.2f;

// ---------------- kernel 0: Wa[s] = W @ a_s  (128x128 each, f32) ----------------
__global__ __launch_bounds__(128) void k_wa(const float* __restrict__ W,
                                            const float* __restrict__ a,
                                            float* __restrict__ Wa) {
  const int i = blockIdx.x;
  const int s = blockIdx.y;
  const int k = threadIdx.x;
  __shared__ float wrow[F];
  wrow[k] = W[i * F + k];
  __syncthreads();
  const float* as = a + s * F * F;
  float acc = 0.f;
#pragma unroll 8
  for (int m = 0; m < F; ++m) acc += wrow[m] * as[m * F + k];
  Wa[(s * F + i) * F + k] = acc;
}

// ---------------- kernel 1: [Wh|E1|E2] = h @ [W|Wa1|Wa2] ----------------
__global__ __launch_bounds__(256) void k_gemm(const float* __restrict__ h,
                                              const float* __restrict__ W,
                                              const float* __restrict__ Wa,
                                              float* __restrict__ Wh,
                                              float* __restrict__ E1,
                                              float* __restrict__ E2) {
  __shared__ float Alds[64][129];
  __shared__ float Blds[128][64];
  const int tid = threadIdx.x;
  const int rb = blockIdx.x * 64;
  const int matc = blockIdx.y >> 1;
  const int cb = (blockIdx.y & 1) * 64;

#pragma unroll
  for (int p = 0; p < 8; ++p) {
    int id = tid + p * 256;
    int row = id >> 5;
    int c0 = (id & 31) * 4;
    float4 v = *reinterpret_cast<const float4*>(&h[(rb + row) * F + c0]);
    Alds[row][c0 + 0] = v.x; Alds[row][c0 + 1] = v.y;
    Alds[row][c0 + 2] = v.z; Alds[row][c0 + 3] = v.w;
  }
  const float* src = (matc == 0) ? W : (Wa + (matc - 1) * F * F);
#pragma unroll
  for (int p = 0; p < 8; ++p) {
    int id = tid + p * 256;
    int k = id >> 4;
    int c0 = (id & 15) * 4;
    float4 v = *reinterpret_cast<const float4*>(&src[k * F + cb + c0]);
    Blds[k][c0 + 0] = v.x; Blds[k][c0 + 1] = v.y;
    Blds[k][c0 + 2] = v.z; Blds[k][c0 + 3] = v.w;
  }
  __syncthreads();

  const int tx = tid & 15;
  const int ty = tid >> 4;
  float acc[4][4] = {};
#pragma unroll 4
  for (int k = 0; k < 128; ++k) {
    float4 bv = *reinterpret_cast<const float4*>(&Blds[k][tx * 4]);
    float a0 = Alds[ty * 4 + 0][k];
    float a1 = Alds[ty * 4 + 1][k];
    float a2 = Alds[ty * 4 + 2][k];
    float a3 = Alds[ty * 4 + 3][k];
    acc[0][0] += a0 * bv.x; acc[0][1] += a0 * bv.y; acc[0][2] += a0 * bv.z; acc[0][3] += a0 * bv.w;
    acc[1][0] += a1 * bv.x; acc[1][1] += a1 * bv.y; acc[1][2] += a1 * bv.z; acc[1][3] += a1 * bv.w;
    acc[2][0] += a2 * bv.x; acc[2][1] += a2 * bv.y; acc[2][2] += a2 * bv.z; acc[2][3] += a2 * bv.w;
    acc[3][0] += a3 * bv.x; acc[3][1] += a3 * bv.y; acc[3][2] += a3 * bv.z; acc[3][3] += a3 * bv.w;
  }

  float* Dp = (matc == 0) ? Wh : ((matc == 1) ? E1 : E2);
  const int gr0 = rb + ty * 4;
  const int c0 = cb + tx * 4;
#pragma unroll
  for (int i = 0; i < 4; ++i) {
    float4 v;
    v.x = acc[i][0]; v.y = acc[i][1]; v.z = acc[i][2]; v.w = acc[i][3];
    *reinterpret_cast<float4*>(&Dp[(gr0 + i) * F + c0]) = v;
  }
}

// ---------------- kernel 2: attention — 4 waves cooperate on one (t,b) row ----
// Block 256 = 4 waves; wave w owns j-strip [w*32, w*32+32). Pass A: partial
// softmax denominator + h' accumulator (uniform adj branch, float2/lane).
// LDS reduce (4.5 KB). Pass B: float4/lane stores, 2 j-rows per iteration,
// branchless adj select. Grid 2560 blocks -> 8 blocks/CU (wave cap), 32 waves/CU.
__global__ __launch_bounds__(256) void k_attn(const float* __restrict__ Wh,
                                              const float* __restrict__ E1,
                                              const float* __restrict__ E2,
                                              const float* __restrict__ adj,
                                              float* __restrict__ out,
                                              float* __restrict__ att) {
  __shared__ float sA[4][F];
  __shared__ float hA[4][F];
  __shared__ float invA[F];

  const int r = blockIdx.x;               // 0..2559
  const int t = r >> 7;
  const int b = r & 127;
  const int w = threadIdx.x >> 6;
  const int lane = threadIdx.x & 63;
  const int fc = lane * 2;
  const int j0 = w * 32;

  const float* E2t = E2 + t * V * F;
  const float* Wht = Wh + t * V * F;
  const float* adjb = adj + b * V;
  const float2 e1v = *reinterpret_cast<const float2*>(E1 + r * F + fc);

  // ---- pass A: partial sums over this wave's j-strip ----
  float s0 = 0.f, s1 = 0.f, h0 = 0.f, h1 = 0.f;
#pragma unroll 4
  for (int jj = 0; jj < 32; ++jj) {
    const int j = j0 + jj;
    if (adjb[j] > 0.f) {                  // wave-uniform branch
      float2 e2 = *reinterpret_cast<const float2*>(E2t + j * F + fc);
      float x0 = e1v.x + e2.x, x1 = e1v.y + e2.y;
      x0 = x0 > 0.f ? x0 : ALPHA * x0;
      x1 = x1 > 0.f ? x1 : ALPHA * x1;
      float p0 = __expf(x0), p1 = __expf(x1);
      float2 wv = *reinterpret_cast<const float2*>(Wht + j * F + fc);
      s0 += p0; s1 += p1;
      h0 += p0 * wv.x; h1 += p1 * wv.y;
    }
  }
  sA[w][fc] = s0; sA[w][fc + 1] = s1;
  hA[w][fc] = h0; hA[w][fc + 1] = h1;
  __syncthreads();

  // ---- reduce across the 4 waves ----
  const float S0 = sA[0][fc] + sA[1][fc] + sA[2][fc] + sA[3][fc];
  const float S1 = sA[0][fc + 1] + sA[1][fc + 1] + sA[2][fc + 1] + sA[3][fc + 1];
  const bool uni = (S0 == 0.f);           // all-masked row: softmax -> uniform 1/V
  const float inv0 = uni ? (1.f / (float)V) : (1.f / S0);
  const float inv1 = uni ? (1.f / (float)V) : (1.f / S1);
  if (w == 0) { invA[fc] = inv0; invA[fc + 1] = inv1; }

  if (w == 0) {
    float H0, H1;
    if (uni) {
      H0 = 0.f; H1 = 0.f;
      for (int j = 0; j < V; ++j) {
        float2 wv = *reinterpret_cast<const float2*>(Wht + j * F + fc);
        H0 += wv.x; H1 += wv.y;
      }
      H0 *= inv0; H1 *= inv1;
    } else {
      H0 = (hA[0][fc] + hA[1][fc] + hA[2][fc] + hA[3][fc]) * inv0;
      H1 = (hA[0][fc + 1] + hA[1][fc + 1] + hA[2][fc + 1] + hA[3][fc + 1]) * inv1;
    }
    float2 ov;
    ov.x = H0 > 0.f ? H0 : __expf(H0) - 1.f;
    ov.y = H1 > 0.f ? H1 : __expf(H1) - 1.f;
    *reinterpret_cast<float2*>(out + r * F + fc) = ov;
  }
  __syncthreads();

  // ---- pass B: float4 stores, 2 j-rows per iteration, branchless ----
  const int jh = lane >> 5;               // which of the 2 j-rows this lane covers
  const int f4 = (lane & 31) * 4;
  const float4 e1q = *reinterpret_cast<const float4*>(E1 + r * F + f4);
  const float4 invq = *reinterpret_cast<const float4*>(&invA[f4]);
  float* attb = att + (size_t)r * (V * F);

#pragma unroll 4
  for (int jj = 0; jj < 16; ++jj) {
    const int j = j0 + jj * 2 + jh;
    const float av = adjb[j];
    const float4 e2q = *reinterpret_cast<const float4*>(E2t + j * F + f4);
    float x0 = e1q.x + e2q.x, x1 = e1q.y + e2q.y;
    float x2 = e1q.z + e2q.z, x3 = e1q.w + e2q.w;
    x0 = x0 > 0.f ? x0 : ALPHA * x0;
    x1 = x1 > 0.f ? x1 : ALPHA * x1;
    x2 = x2 > 0.f ? x2 : ALPHA * x2;
    x3 = x3 > 0.f ? x3 : ALPHA * x3;
    float4 o;
    o.x = __expf(x0) * invq.x;
    o.y = __expf(x1) * invq.y;
    o.z = __expf(x2) * invq.z;
    o.w = __expf(x3) * invq.w;
    if (uni) {
      o.x = invq.x; o.y = invq.y; o.z = invq.z; o.w = invq.w;
    } else if (av <= 0.f) {
      o.x = 0.f; o.y = 0.f; o.z = 0.f; o.w = 0.f;
    }
    *reinterpret_cast<float4*>(attb + j * F + f4) = o;
  }
}

extern "C" void kernel_launch(void* const* d_in, const int* in_sizes, int n_in,
                              void* d_out, int out_size, void* d_ws, size_t ws_size,
                              hipStream_t stream) {
  (void)in_sizes; (void)n_in; (void)out_size; (void)ws_size;
  const float* h   = (const float*)d_in[0];
  const float* adj = (const float*)d_in[1];
  const float* W   = (const float*)d_in[2];
  const float* a   = (const float*)d_in[3];

  float* Wh = (float*)d_ws;
  float* E1 = Wh + NTIME * V * F;
  float* E2 = E1 + NTIME * V * F;
  float* Wa = E2 + NTIME * V * F;

  float* out = (float*)d_out;                    // (T, V, F)
  float* att = out + NTIME * V * F;              // (T, V, V, F)

  k_wa<<<dim3(128, 2), 128, 0, stream>>>(W, a, Wa);
  k_gemm<<<dim3(40, 6), 256, 0, stream>>>(h, W, Wa, Wh, E1, E2);
  k_attn<<<dim3(NTIME * V), 256, 0, stream>>>(Wh, E1, E2, adj, out, att);
}